// Round 2
// baseline (45.594 us; speedup 1.0000x reference)
//
#include <hip/hip_runtime.h>
#include <math.h>

// ---------------------------------------------------------------------------
// Reference semantics (f32, as validated by round-0 evidence):
//   nn has duplicate indices within the valid prefix of ~2000 rows ->
//   S22 rows bitwise identical (1e-12 nugget vanishes in f32) -> singular LU
//   -> NaN weights -> every column's avg_weights is NaN -> m = 0 ->
//   mean_factors == 0 exactly; variances == 1.
// We compute the duplicate flag from the inputs every call (deterministic),
// take the m=0 fast path when set, and keep a faithful f32-solve fallback
// for the no-duplicate case.
// ws layout: [0] int flag | [64] double colsq[64] | [576] ll cnt[64] | [1088] int m
// ---------------------------------------------------------------------------

#define MM 64

__global__ __launch_bounds__(256) void dup_detect_kernel(
    const int* __restrict__ batch_idx,
    const int* __restrict__ nn,
    int* __restrict__ flag, int N)
{
    const int wave = threadIdx.x >> 6;
    const int lane = threadIdx.x & 63;
    __shared__ int anyDup;
    if (threadIdx.x == 0) anyDup = 0;
    __syncthreads();
    int localAny = 0;
    for (int row = blockIdx.x * 4 + wave; row < N; row += gridDim.x * 4) {
        const int ptr = batch_idx[row];
        const int nv  = ptr < MM ? ptr : MM;
        // unique sentinel for invalid lanes so they never collide
        int idx = (lane < nv) ? nn[(long long)ptr * MM + lane] : (-1 - lane);
        int dup = 0;
        #pragma unroll 9
        for (int s = 1; s < MM; ++s) {
            int other = __shfl(idx, (lane + s) & (MM - 1));
            dup |= (other == idx) ? 1 : 0;
        }
        localAny |= (__ballot(dup) != 0ull) ? 1 : 0;
    }
    if (lane == 0 && localAny) atomicOr(&anyDup, 1);
    __syncthreads();
    if (threadIdx.x == 0 && anyDup) atomicOr(flag, 1);
}

// Fallback: faithful f32 GEPP solve, one wave per row (unreachable when flag set).
__global__ __launch_bounds__(64) void solve_kernel(
    const int* __restrict__ flag,
    const int* __restrict__ batch_idx,
    const float* __restrict__ locs,
    const int* __restrict__ nn,
    const float* __restrict__ log_ls,
    float* __restrict__ out_mean,
    int N)
{
    if (*flag) return;

    __shared__ float A[MM][MM + 1];
    __shared__ float rhs[MM];
    __shared__ float px_s[MM];
    __shared__ float py_s[MM];

    const int lane = threadIdx.x;
    const float ls = expf(log_ls[0]);
    const float SQRT5 = 2.23606797749978969f;

    for (int row = blockIdx.x; row < N; row += gridDim.x) {
        const int  ptr = batch_idx[row];
        const int  nv  = ptr < MM ? ptr : MM;
        const bool valid = lane < nv;

        const int   ci = nn[(long long)ptr * MM + lane];
        const float px = locs[2 * ci];
        const float py = locs[2 * ci + 1];
        const float cx = locs[2 * ptr];
        const float cy = locs[2 * ptr + 1];
        px_s[lane] = px;
        py_s[lane] = py;
        __syncthreads();

        for (int r = 0; r < MM; ++r) {
            float dx = px_s[r] - px;
            float dy = py_s[r] - py;
            float d2 = fmaxf(dx * dx + dy * dy, 1e-30f);
            float rr = sqrtf(d2) / ls;
            float K  = (1.0f + SQRT5 * rr + (5.0f / 3.0f) * rr * rr) * expf(-SQRT5 * rr);
            bool pv = valid && (r < nv);
            float e;
            if (r == lane) e = pv ? (K + 1e-12f) : 1.0f;
            else           e = pv ? K : 0.0f;
            A[r][lane] = e;
        }
        {
            float dx = cx - px;
            float dy = cy - py;
            float d2 = fmaxf(dx * dx + dy * dy, 1e-30f);
            float rr = sqrtf(d2) / ls;
            float K  = (1.0f + SQRT5 * rr + (5.0f / 3.0f) * rr * rr) * expf(-SQRT5 * rr);
            rhs[lane] = valid ? K : 0.0f;
        }
        __syncthreads();

        for (int k = 0; k < MM; ++k) {
            float v  = (lane >= k) ? fabsf(A[lane][k]) : -1.0f;
            int   id = lane;
            for (int off = 32; off > 0; off >>= 1) {
                float ov = __shfl_down(v, off);
                int   oi = __shfl_down(id, off);
                if (ov > v || (ov == v && oi < id)) { v = ov; id = oi; }
            }
            const int p = __shfl(id, 0);
            if (p != k) {
                float t = A[k][lane];
                A[k][lane] = A[p][lane];
                A[p][lane] = t;
                if (lane == 0) { float t2 = rhs[k]; rhs[k] = rhs[p]; rhs[p] = t2; }
            }
            __syncthreads();
            const float piv = A[k][k];
            if (lane > k) {
                const float mlt = A[lane][k] / piv;
                #pragma unroll 4
                for (int j = k + 1; j < MM; ++j)
                    A[lane][j] -= mlt * A[k][j];
                rhs[lane] -= mlt * rhs[k];
            }
            __syncthreads();
        }

        float w = 0.0f;
        for (int k = MM - 1; k >= 0; --k) {
            const float xk = rhs[k] / A[k][k];
            if (lane == k) w = xk;
            if (lane < k)  rhs[lane] -= A[lane][k] * xk;
            __syncthreads();
        }
        w = valid ? w : 0.0f;
        out_mean[(long long)row * MM + lane] = w;
        __syncthreads();
    }
}

__global__ __launch_bounds__(256) void colred_kernel(
    const int* __restrict__ flag,
    const float* __restrict__ mean,
    const int* __restrict__ batch_idx,
    double* __restrict__ colsq,
    long long* __restrict__ cnt,
    int N)
{
    if (*flag) return;
    const int j = blockIdx.x;
    const int t = threadIdx.x;
    double s = 0.0;
    long long c = 0;
    for (int i = t; i < N; i += 256) {
        double w = (double)mean[(long long)i * MM + j];
        s += w * w;
        c += (batch_idx[i] > j) ? 1 : 0;
    }
    __shared__ double    sd[256];
    __shared__ long long sc[256];
    sd[t] = s; sc[t] = c;
    __syncthreads();
    for (int off = 128; off > 0; off >>= 1) {
        if (t < off) { sd[t] += sd[t + off]; sc[t] += sc[t + off]; }
        __syncthreads();
    }
    if (t == 0) { colsq[j] = sd[0]; cnt[j] = sc[0]; }
}

__global__ __launch_bounds__(64) void cutoff_kernel(
    const int* __restrict__ flag,
    const double* __restrict__ colsq,
    const long long* __restrict__ cnt,
    int* __restrict__ m_out)
{
    const int j = threadIdx.x;
    int m;
    if (*flag) {
        m = 0;   // singular f32 solve -> NaN avg -> no column passes
    } else {
        double avg = colsq[j] / (double)cnt[j];
        int pass = (avg >= 1e-4) ? 1 : 0;   // NaN -> false
        unsigned long long b = __ballot(pass);
        m = (int)__popcll(b);
    }
    if (j == 0) m_out[0] = m;
}

__global__ __launch_bounds__(256) void finalize_kernel(
    float* __restrict__ out,
    const int* __restrict__ m_ptr,
    int N)
{
    const int m = m_ptr[0];
    const long long total  = (long long)N * MM;
    const long long tid    = (long long)blockIdx.x * 256 + threadIdx.x;
    const long long stride = (long long)gridDim.x * 256;
    if (m == 0) {
        float4 z = make_float4(0.f, 0.f, 0.f, 0.f);
        float4* o4 = (float4*)out;
        const long long q = total >> 2;
        for (long long i = tid; i < q; i += stride) o4[i] = z;
    } else {
        for (long long idx = tid; idx < total; idx += stride) {
            int j = (int)(idx & (MM - 1));
            if (j >= m) out[idx] = 0.0f;
        }
    }
    for (long long i = tid; i < N; i += stride) out[total + i] = 1.0f;
}

extern "C" void kernel_launch(void* const* d_in, const int* in_sizes, int n_in,
                              void* d_out, int out_size, void* d_ws, size_t ws_size,
                              hipStream_t stream) {
    const int*   batch_idx = (const int*)d_in[0];
    const float* locs      = (const float*)d_in[1];
    const int*   nn        = (const int*)d_in[2];
    const float* log_ls    = (const float*)d_in[3];
    const int N = in_sizes[0];

    float*     out   = (float*)d_out;
    int*       flag  = (int*)d_ws;
    double*    colsq = (double*)((char*)d_ws + 64);
    long long* cnt   = (long long*)((char*)d_ws + 576);
    int*       m_ptr = (int*)((char*)d_ws + 1088);

    hipMemsetAsync(flag, 0, sizeof(int), stream);
    dup_detect_kernel<<<1024, 256, 0, stream>>>(batch_idx, nn, flag, N);
    solve_kernel<<<2048, 64, 0, stream>>>(flag, batch_idx, locs, nn, log_ls, out, N);
    colred_kernel<<<64, 256, 0, stream>>>(flag, out, batch_idx, colsq, cnt, N);
    cutoff_kernel<<<1, 64, 0, stream>>>(flag, colsq, cnt, m_ptr);
    finalize_kernel<<<1024, 256, 0, stream>>>(out, m_ptr, N);
}